// Round 5
// baseline (1243.062 us; speedup 1.0000x reference)
//
#include <hip/hip_runtime.h>

#define NB   16
#define NN   2048
#define NPTS (NB * NN)
#define KNB  6

#define CINF __int_as_float(0x7F800000)

// ---------------- weight prep: transpose the three W1s ----------------
__global__ void prep_w(const float* __restrict__ W10, const float* __restrict__ W11,
                       const float* __restrict__ W12,
                       float* __restrict__ T0, float* __restrict__ T1,
                       float* __restrict__ T2) {
    int t = blockIdx.x * 256 + threadIdx.x;
    if (t < 4096) { int o = t >> 6, c = t & 63;  T0[o * 64 + c]  = W10[c * 64 + o]; }
    if (t < 4096) { int o = t >> 7, c = t & 127; T1[o * 128 + c] = W11[c * 32 + o]; }
    if (t < 4096) { int o = t >> 6, c = t & 63;  T2[o * 64 + c]  = W12[c * 64 + o]; }
}

// wave-wide min via DPP (rocPRIM gfx9 sequence); returns uniform min of x.
__device__ __forceinline__ float wave_min64(float x) {
    float v = x;
    v = fminf(v, __int_as_float(__builtin_amdgcn_update_dpp(
            __float_as_int(v), __float_as_int(v), 0x111, 0xf, 0xf, false)));
    v = fminf(v, __int_as_float(__builtin_amdgcn_update_dpp(
            __float_as_int(v), __float_as_int(v), 0x112, 0xf, 0xf, false)));
    v = fminf(v, __int_as_float(__builtin_amdgcn_update_dpp(
            __float_as_int(v), __float_as_int(v), 0x114, 0xf, 0xf, false)));
    v = fminf(v, __int_as_float(__builtin_amdgcn_update_dpp(
            __float_as_int(v), __float_as_int(v), 0x118, 0xf, 0xf, false)));
    v = fminf(v, __int_as_float(__builtin_amdgcn_update_dpp(
            __float_as_int(v), __float_as_int(v), 0x142, 0xa, 0xf, false)));
    v = fminf(v, __int_as_float(__builtin_amdgcn_update_dpp(
            __float_as_int(v), __float_as_int(v), 0x143, 0xc, 0xf, false)));
    return __int_as_float(__builtin_amdgcn_readlane(__float_as_int(v), 63));
}

__device__ __forceinline__ void cswap(float& a, int& ta, float& b, int& tb) {
    const bool c = b < a;                 // strict: keeps lower row id on ties
    const float nv = c ? b : a; const float xv = c ? a : b;
    const int   nt = c ? tb : ta; const int   xt = c ? ta : tb;
    a = nv; b = xv; ta = nt; tb = xt;
}

// ---------------- kNN scan kernel ----------------
// wave = 64*R candidates resident in VGPRs (rows loaded once, sq computed on
// the fly). Loop over NQ queries: query row via wave-uniform scalar loads,
// R*C v_fmac per query, then 6 rounds of DPP wave-min + ballot -> exact
// sorted top-6, written as packed u64 keys to plist[z].  Zero LDS.
template<int C, int R, int SPL, int NQ>
__global__ __launch_bounds__(256, 2)
void knn_scan(const float* __restrict__ x, unsigned long long* __restrict__ plist) {
    const int lane  = threadIdx.x & 63;
    const int w     = threadIdx.x >> 6;
    const int b     = blockIdx.y;
    const int base  = b * NN;
    const int z     = blockIdx.z * 4 + w;        // 0..SPL-1
    const int cbase = z * (R * 64);
    const int qbase = blockIdx.x * NQ;

    // ---- load R candidate rows into registers; compute their |x|^2
    float row[R][C];
    float sqr[R];
    int   cand[R];
#pragma unroll
    for (int r = 0; r < R; ++r) {
        cand[r] = cbase + r * 64 + lane;
        const float* rp = x + (size_t)(base + cand[r]) * C;
        float s = 0.f;
#pragma unroll
        for (int c = 0; c < C; c += 4) {
            float4 f = *(const float4*)(rp + c);
            row[r][c] = f.x; row[r][c + 1] = f.y;
            row[r][c + 2] = f.z; row[r][c + 3] = f.w;
            s += f.x * f.x + f.y * f.y + f.z * f.z + f.w * f.w;
        }
        sqr[r] = s;
    }

    for (int qi = 0; qi < NQ; ++qi) {
        const int q = qbase + qi;
        const float* qp = x + (size_t)(base + q) * C;   // uniform -> s_load
        float acc[R];
#pragma unroll
        for (int r = 0; r < R; ++r) acc[r] = 0.f;
#pragma unroll
        for (int c = 0; c < C; ++c) {
            const float qv = qp[c];
#pragma unroll
            for (int r = 0; r < R; ++r) acc[r] = fmaf(row[r][c], qv, acc[r]);
        }

        // scores (query-side norm dropped: ordering-invariant), self-excluded
        float s[R]; int t[R];
#pragma unroll
        for (int r = 0; r < R; ++r) {
            const float v = fmaf(-2.f, acc[r], sqr[r]);
            s[r] = (cand[r] == q) ? CINF : v;
            t[r] = r;
        }
        // per-lane ascending sort of R entries
        if (R == 2) {
            cswap(s[0], t[0], s[1], t[1]);
        } else if (R == 4) {
            cswap(s[0], t[0], s[1], t[1]);
            cswap(s[2], t[2], s[3], t[3]);
            cswap(s[0], t[0], s[2], t[2]);
            cswap(s[1], t[1], s[3], t[3]);
            cswap(s[1], t[1], s[2], t[2]);
        }

        unsigned long long keyv = ~0ull;
#pragma unroll
        for (int k = 0; k < KNB; ++k) {
            const float m = wave_min64(s[0]);
            const unsigned long long ball = __ballot(s[0] == m);
            const int lsel = (int)__builtin_ctzll(ball);
            const int rtag = __builtin_amdgcn_readlane(t[0], lsel);
            const int cidx = cbase + rtag * 64 + lsel;   // batch-local
            unsigned mu = __float_as_uint(m);
            mu ^= (mu & 0x80000000u) ? 0xFFFFFFFFu : 0x80000000u;
            const unsigned long long key =
                ((unsigned long long)mu << 11) | (unsigned)cidx;
            if (lane == k) keyv = key;
            const bool me = (lane == lsel);
#pragma unroll
            for (int r = 0; r < R - 1; ++r) {
                s[r] = me ? s[r + 1] : s[r];
                t[r] = me ? t[r + 1] : t[r];
            }
            s[R - 1] = me ? CINF : s[R - 1];
        }
        if (lane < KNB)
            plist[((size_t)z * NPTS + (base + q)) * KNB + lane] = keyv;
    }
}

// ---------------- edge MLP kernel (merge fused in prologue) ----------------
// Phase A: threads 0..63 merge SPL sorted 6-lists -> nbr indices in LDS.
// Phase B: block = 6 waves; lane = point; wave = neighbor; weight loads are
// wave-uniform scalar broadcasts; 6->1 max via 3-barrier LDS tree.
template<int CIN, int COUT, int SPL, bool RESID, int MINW>
__global__ __launch_bounds__(384, MINW)
void mlp_kernel(const float* __restrict__ xin,
                const unsigned long long* __restrict__ plist,
                const float* __restrict__ W1T, const float* __restrict__ b1,
                const float* __restrict__ W2,  const float* __restrict__ b2,
                const float* __restrict__ resid, float* __restrict__ out) {
    constexpr int RS = COUT + 4;
    __shared__ float Buf[3][64][RS];
    __shared__ int   nbrs[64][KNB];

    const int lane = threadIdx.x & 63;
    const int w    = __builtin_amdgcn_readfirstlane(threadIdx.x >> 6);  // 0..5
    const int i    = blockIdx.x * 64 + lane;

    // ---- phase A: merge partial lists for this block's 64 points
    if (threadIdx.x < 64) {
        unsigned long long best[KNB];
#pragma unroll
        for (int k = 0; k < KNB; ++k) best[k] = ~0ull;
        for (int z = 0; z < SPL; ++z) {
            const unsigned long long* p = plist + ((size_t)z * NPTS + i) * KNB;
            for (int e = 0; e < KNB; ++e) {
                const unsigned long long v = p[e];
                if (v >= best[KNB - 1]) break;    // sublist ascending
                best[KNB - 1] = v;
#pragma unroll
                for (int k = KNB - 2; k >= 0; --k) {
                    if (best[k + 1] < best[k]) {
                        unsigned long long tt = best[k];
                        best[k] = best[k + 1]; best[k + 1] = tt;
                    }
                }
            }
        }
        const int bb = (i >> 11) << 11;
#pragma unroll
        for (int k = 0; k < KNB; ++k)
            nbrs[threadIdx.x][k] = bb + (int)(best[k] & 2047ull);
    }
    __syncthreads();

    // ---- phase B
    float xi[CIN], xd[CIN];
    {
        const float* xp = xin + (size_t)i * CIN;
#pragma unroll
        for (int c = 0; c < CIN; c += 4) {
            float4 f = *(const float4*)(xp + c);
            xi[c] = f.x; xi[c + 1] = f.y; xi[c + 2] = f.z; xi[c + 3] = f.w;
        }
        const int j = nbrs[lane][w];
        const float* jp = xin + (size_t)j * CIN;
#pragma unroll
        for (int c = 0; c < CIN; c += 4) {
            float4 f = *(const float4*)(jp + c);
            xd[c]     = f.x - xi[c];     xd[c + 1] = f.y - xi[c + 1];
            xd[c + 2] = f.z - xi[c + 2]; xd[c + 3] = f.w - xi[c + 3];
        }
    }

    float uacc[COUT];
#pragma unroll
    for (int o = 0; o < COUT; ++o) uacc[o] = 0.f;

    for (int op = 0; op < COUT; ++op) {
        const float* w1r = W1T + (size_t)op * (2 * CIN);
        float h0 = 0.f, h1 = 0.f, h2 = 0.f, h3 = 0.f;
#pragma unroll
        for (int c = 0; c < CIN; c += 4) {
            h0 = fmaf(w1r[c],     xi[c],     h0);
            h1 = fmaf(w1r[c + 1], xi[c + 1], h1);
            h2 = fmaf(w1r[c + 2], xi[c + 2], h2);
            h3 = fmaf(w1r[c + 3], xi[c + 3], h3);
        }
#pragma unroll
        for (int c = 0; c < CIN; c += 4) {
            h0 = fmaf(w1r[CIN + c],     xd[c],     h0);
            h1 = fmaf(w1r[CIN + c + 1], xd[c + 1], h1);
            h2 = fmaf(w1r[CIN + c + 2], xd[c + 2], h2);
            h3 = fmaf(w1r[CIN + c + 3], xd[c + 3], h3);
        }
        const float h = fmaxf((h0 + h1) + (h2 + h3) + b1[op], 0.f);
        const float* w2r = W2 + (size_t)op * COUT;
#pragma unroll
        for (int o = 0; o < COUT; ++o)
            uacc[o] = fmaf(w2r[o], h, uacc[o]);
    }

    if (w >= 3) {
#pragma unroll
        for (int o = 0; o < COUT; ++o) Buf[w - 3][lane][o] = uacc[o];
    }
    __syncthreads();
    if (w < 3) {
#pragma unroll
        for (int o = 0; o < COUT; ++o) uacc[o] = fmaxf(uacc[o], Buf[w][lane][o]);
    }
    __syncthreads();
    if (w == 1 || w == 2) {
#pragma unroll
        for (int o = 0; o < COUT; ++o) Buf[w][lane][o] = uacc[o];
    }
    __syncthreads();
    if (w == 0) {
        float* po = out + (size_t)i * COUT;
#pragma unroll
        for (int o = 0; o < COUT; ++o) {
            float v = fmaxf(uacc[o], fmaxf(Buf[1][lane][o], Buf[2][lane][o])) + b2[o];
            if (RESID) v += resid[(size_t)i * COUT + o];
            po[o] = fmaxf(v, 0.f);
        }
    }
}

extern "C" void kernel_launch(void* const* d_in, const int* in_sizes, int n_in,
                              void* d_out, int out_size, void* d_ws, size_t ws_size,
                              hipStream_t stream) {
    const float* x    = (const float*)d_in[0];
    const float* W1_0 = (const float*)d_in[2];
    const float* b1_0 = (const float*)d_in[3];
    const float* W2_0 = (const float*)d_in[4];
    const float* b2_0 = (const float*)d_in[5];
    const float* W1_1 = (const float*)d_in[6];
    const float* b1_1 = (const float*)d_in[7];
    const float* W2_1 = (const float*)d_in[8];
    const float* b2_1 = (const float*)d_in[9];
    const float* W1_2 = (const float*)d_in[10];
    const float* b1_2 = (const float*)d_in[11];
    const float* W2_2 = (const float*)d_in[12];
    const float* b2_2 = (const float*)d_in[13];
    float* outp = (float*)d_out;

    // workspace layout (plist first for 8B alignment); max SPL = 16
    unsigned long long* plist = (unsigned long long*)d_ws;        // 16*NPTS*6
    float* x0 = (float*)(plist + (size_t)16 * NPTS * KNB);        // 32768 x 64
    float* x1 = x0 + (size_t)NPTS * 64;                           // 32768 x 32
    float* T0 = x1 + (size_t)NPTS * 32;                           // 64 x 64
    float* T1 = T0 + 4096;                                        // 32 x 128
    float* T2 = T1 + 4096;                                        // 64 x 64

    const dim3 g32(32, NB, 2);   // C=32: R=4, SPL=8,  NQ=64  -> 4096 waves
    const dim3 g64(16, NB, 4);   // C=64: R=2, SPL=16, NQ=128 -> 4096 waves
    const int  pgrid = NPTS / 64;

    prep_w<<<16, 256, 0, stream>>>(W1_0, W1_1, W1_2, T0, T1, T2);

    // ---- layer 0: x (32) -> x0 (64), relu ----
    knn_scan<32, 4, 8, 64><<<g32, 256, 0, stream>>>(x, plist);
    mlp_kernel<32, 64, 8, false, 3><<<pgrid, 384, 0, stream>>>(x, plist, T0, b1_0, W2_0, b2_0, nullptr, x0);

    // ---- layer 1: x0 (64) -> x1 (32), relu ----
    knn_scan<64, 2, 16, 128><<<g64, 256, 0, stream>>>(x0, plist);
    mlp_kernel<64, 32, 16, false, 2><<<pgrid, 384, 0, stream>>>(x0, plist, T1, b1_1, W2_1, b2_1, nullptr, x1);

    // ---- layer 2: x1 (32) -> out (64), +x0 residual, relu ----
    knn_scan<32, 4, 8, 64><<<g32, 256, 0, stream>>>(x1, plist);
    mlp_kernel<32, 64, 8, true, 3><<<pgrid, 384, 0, stream>>>(x1, plist, T2, b1_2, W2_2, b2_2, x0, outp);
}

// Round 6
// 997.269 us; speedup vs baseline: 1.2465x; 1.2465x over previous
//
#include <hip/hip_runtime.h>

#define NB   16
#define NN   2048
#define NPTS (NB * NN)
#define KNB  6
#define SPL  8           // candidate ranges per batch (partial top-6 lists)

// ---------------- squared-norm kernel ----------------
template<int C>
__global__ void sq_kernel(const float* __restrict__ x, float* __restrict__ sq) {
    int i = blockIdx.x * blockDim.x + threadIdx.x;
    if (i >= NPTS) return;
    const float4* r = (const float4*)(x + (size_t)i * C);
    float s = 0.f;
#pragma unroll
    for (int c = 0; c < C / 4; ++c) {
        float4 f = r[c];
        s += f.x * f.x + f.y * f.y + f.z * f.z + f.w * f.w;
    }
    sq[i] = s;
}

// ---------------- weight prep: transpose the three W1s ----------------
__global__ void prep_w(const float* __restrict__ W10, const float* __restrict__ W11,
                       const float* __restrict__ W12,
                       float* __restrict__ T0, float* __restrict__ T1,
                       float* __restrict__ T2) {
    int t = blockIdx.x * 256 + threadIdx.x;
    if (t < 4096) { int o = t >> 6, c = t & 63;  T0[o * 64 + c]  = W10[c * 64 + o]; }
    if (t < 4096) { int o = t >> 7, c = t & 127; T1[o * 128 + c] = W11[c * 32 + o]; }
    if (t < 4096) { int o = t >> 6, c = t & 63;  T2[o * 64 + c]  = W12[c * 64 + o]; }
}

// branchless stable insert of (s, j) into ascending 6-list (round-4 validated)
__device__ __forceinline__ void insert6(float s, int j, float* dl, int* il) {
    float cd = s; int ci = j;
#pragma unroll
    for (int k = 0; k < 6; ++k) {
        const float od = dl[k]; const int oi = il[k];
        const bool c = cd < od;          // strict: existing wins ties -> stable
        dl[k] = c ? cd : od;
        il[k] = c ? ci : oi;
        cd = c ? od : cd;
        ci = c ? oi : ci;
    }
}

// ---------------- kNN scan kernel ----------------
// lane = query (row in VGPRs). Candidates + sq stream through the SCALAR pipe
// (wave-uniform s_load broadcast, zero LDS). Branchless insert6 keeps the
// body straight-line so next-iteration s_loads hoist above the FMA block.
// grid (NN/256, NB, SPL); block = 4 waves, all on the same candidate range z.
template<int C, int MINW>
__global__ __launch_bounds__(256, MINW)
void knn_scan(const float* __restrict__ x, const float* __restrict__ sq,
              unsigned long long* __restrict__ plist) {
    constexpr int RANGE = NN / SPL;      // 256
    const int lane = threadIdx.x & 63;
    const int w    = threadIdx.x >> 6;
    const int b    = blockIdx.y;
    const int z    = blockIdx.z;
    const int base = b * NN;
    const int q    = blockIdx.x * 256 + w * 64 + lane;   // batch-local query
    const int cbase = z * RANGE;

    // per-lane query row in registers
    float qr[C];
    {
        const float* qp = x + (size_t)(base + q) * C;
#pragma unroll
        for (int c = 0; c < C; c += 4) {
            float4 f = *(const float4*)(qp + c);
            qr[c] = f.x; qr[c + 1] = f.y; qr[c + 2] = f.z; qr[c + 3] = f.w;
        }
    }

    float dl[6]; int il[6];
#pragma unroll
    for (int k = 0; k < 6; ++k) { dl[k] = 1e30f; il[k] = 0; }

    const float* rp  = x + (size_t)(base + cbase) * C;   // uniform base
    const float* sqp = sq + base + cbase;                // uniform base

    for (int j = 0; j < RANGE; ++j) {
        const float* row = rp + (size_t)j * C;           // uniform -> s_load
        float a0 = 0.f, a1 = 0.f, a2 = 0.f, a3 = 0.f;
#pragma unroll
        for (int c = 0; c < C; c += 4) {
            a0 = fmaf(row[c],     qr[c],     a0);
            a1 = fmaf(row[c + 1], qr[c + 1], a1);
            a2 = fmaf(row[c + 2], qr[c + 2], a2);
            a3 = fmaf(row[c + 3], qr[c + 3], a3);
        }
        const int jj = cbase + j;
        float s = fmaf(-2.f, (a0 + a1) + (a2 + a3), sqp[j]);
        s = (jj == q) ? 1e30f : s;       // self-exclusion
        insert6(s, jj, dl, il);
    }

    // packed sortable keys: (flip(score) << 11) | cand_idx (ascending)
    unsigned long long* o = plist + ((size_t)z * NPTS + (base + q)) * KNB;
#pragma unroll
    for (int k = 0; k < 6; ++k) {
        unsigned u = __float_as_uint(dl[k]);
        u ^= (u & 0x80000000u) ? 0xFFFFFFFFu : 0x80000000u;
        o[k] = ((unsigned long long)u << 11) | (unsigned)(il[k] & 2047);
    }
}

// ---------------- edge MLP kernel (merge fused in prologue) ----------------
// Phase A: threads 0..63 merge SPL sorted 6-lists -> nbr indices in LDS.
// Phase B: block = 6 waves; lane = point; wave = neighbor; weight loads are
// wave-uniform scalar broadcasts; 6->1 max via 3-barrier LDS tree.
template<int CIN, int COUT, bool RESID, int MINW>
__global__ __launch_bounds__(384, MINW)
void mlp_kernel(const float* __restrict__ xin,
                const unsigned long long* __restrict__ plist,
                const float* __restrict__ W1T, const float* __restrict__ b1,
                const float* __restrict__ W2,  const float* __restrict__ b2,
                const float* __restrict__ resid, float* __restrict__ out) {
    constexpr int RS = COUT + 4;
    __shared__ float Buf[3][64][RS];
    __shared__ int   nbrs[64][KNB];

    const int lane = threadIdx.x & 63;
    const int w    = __builtin_amdgcn_readfirstlane(threadIdx.x >> 6);  // 0..5
    const int i    = blockIdx.x * 64 + lane;

    // ---- phase A: merge partial lists for this block's 64 points
    if (threadIdx.x < 64) {
        unsigned long long best[KNB];
#pragma unroll
        for (int k = 0; k < KNB; ++k) best[k] = ~0ull;
        for (int z = 0; z < SPL; ++z) {
            const unsigned long long* p = plist + ((size_t)z * NPTS + i) * KNB;
            for (int e = 0; e < KNB; ++e) {
                const unsigned long long v = p[e];
                if (v >= best[KNB - 1]) break;    // sublist ascending
                best[KNB - 1] = v;
#pragma unroll
                for (int k = KNB - 2; k >= 0; --k) {
                    if (best[k + 1] < best[k]) {
                        unsigned long long tt = best[k];
                        best[k] = best[k + 1]; best[k + 1] = tt;
                    }
                }
            }
        }
        const int bb = (i >> 11) << 11;
#pragma unroll
        for (int k = 0; k < KNB; ++k)
            nbrs[threadIdx.x][k] = bb + (int)(best[k] & 2047ull);
    }
    __syncthreads();

    // ---- phase B
    float xi[CIN], xd[CIN];
    {
        const float* xp = xin + (size_t)i * CIN;
#pragma unroll
        for (int c = 0; c < CIN; c += 4) {
            float4 f = *(const float4*)(xp + c);
            xi[c] = f.x; xi[c + 1] = f.y; xi[c + 2] = f.z; xi[c + 3] = f.w;
        }
        const int j = nbrs[lane][w];
        const float* jp = xin + (size_t)j * CIN;
#pragma unroll
        for (int c = 0; c < CIN; c += 4) {
            float4 f = *(const float4*)(jp + c);
            xd[c]     = f.x - xi[c];     xd[c + 1] = f.y - xi[c + 1];
            xd[c + 2] = f.z - xi[c + 2]; xd[c + 3] = f.w - xi[c + 3];
        }
    }

    float uacc[COUT];
#pragma unroll
    for (int o = 0; o < COUT; ++o) uacc[o] = 0.f;

    for (int op = 0; op < COUT; ++op) {
        const float* w1r = W1T + (size_t)op * (2 * CIN);
        float h0 = 0.f, h1 = 0.f, h2 = 0.f, h3 = 0.f;
#pragma unroll
        for (int c = 0; c < CIN; c += 4) {
            h0 = fmaf(w1r[c],     xi[c],     h0);
            h1 = fmaf(w1r[c + 1], xi[c + 1], h1);
            h2 = fmaf(w1r[c + 2], xi[c + 2], h2);
            h3 = fmaf(w1r[c + 3], xi[c + 3], h3);
        }
#pragma unroll
        for (int c = 0; c < CIN; c += 4) {
            h0 = fmaf(w1r[CIN + c],     xd[c],     h0);
            h1 = fmaf(w1r[CIN + c + 1], xd[c + 1], h1);
            h2 = fmaf(w1r[CIN + c + 2], xd[c + 2], h2);
            h3 = fmaf(w1r[CIN + c + 3], xd[c + 3], h3);
        }
        const float h = fmaxf((h0 + h1) + (h2 + h3) + b1[op], 0.f);
        const float* w2r = W2 + (size_t)op * COUT;
#pragma unroll
        for (int o = 0; o < COUT; ++o)
            uacc[o] = fmaf(w2r[o], h, uacc[o]);
    }

    if (w >= 3) {
#pragma unroll
        for (int o = 0; o < COUT; ++o) Buf[w - 3][lane][o] = uacc[o];
    }
    __syncthreads();
    if (w < 3) {
#pragma unroll
        for (int o = 0; o < COUT; ++o) uacc[o] = fmaxf(uacc[o], Buf[w][lane][o]);
    }
    __syncthreads();
    if (w == 1 || w == 2) {
#pragma unroll
        for (int o = 0; o < COUT; ++o) Buf[w][lane][o] = uacc[o];
    }
    __syncthreads();
    if (w == 0) {
        float* po = out + (size_t)i * COUT;
#pragma unroll
        for (int o = 0; o < COUT; ++o) {
            float v = fmaxf(uacc[o], fmaxf(Buf[1][lane][o], Buf[2][lane][o])) + b2[o];
            if (RESID) v += resid[(size_t)i * COUT + o];
            po[o] = fmaxf(v, 0.f);
        }
    }
}

extern "C" void kernel_launch(void* const* d_in, const int* in_sizes, int n_in,
                              void* d_out, int out_size, void* d_ws, size_t ws_size,
                              hipStream_t stream) {
    const float* x    = (const float*)d_in[0];
    const float* W1_0 = (const float*)d_in[2];
    const float* b1_0 = (const float*)d_in[3];
    const float* W2_0 = (const float*)d_in[4];
    const float* b2_0 = (const float*)d_in[5];
    const float* W1_1 = (const float*)d_in[6];
    const float* b1_1 = (const float*)d_in[7];
    const float* W2_1 = (const float*)d_in[8];
    const float* b2_1 = (const float*)d_in[9];
    const float* W1_2 = (const float*)d_in[10];
    const float* b1_2 = (const float*)d_in[11];
    const float* W2_2 = (const float*)d_in[12];
    const float* b2_2 = (const float*)d_in[13];
    float* outp = (float*)d_out;

    // workspace layout (plist first for 8B alignment)
    unsigned long long* plist = (unsigned long long*)d_ws;        // SPL*NPTS*6
    float* x0  = (float*)(plist + (size_t)SPL * NPTS * KNB);      // 32768 x 64
    float* x1  = x0 + (size_t)NPTS * 64;                          // 32768 x 32
    float* sqb = x1 + (size_t)NPTS * 32;                          // 32768
    float* T0  = sqb + NPTS;                                      // 64 x 64
    float* T1  = T0 + 4096;                                       // 32 x 128
    float* T2  = T1 + 4096;                                       // 64 x 64

    const dim3 gscan(NN / 256, NB, SPL);   // (8,16,8) x 256 thr = 4096 waves
    const int  sgrid = NPTS / 256;
    const int  pgrid = NPTS / 64;

    prep_w<<<16, 256, 0, stream>>>(W1_0, W1_1, W1_2, T0, T1, T2);

    // ---- layer 0: x (32) -> x0 (64), relu ----
    sq_kernel<32><<<sgrid, 256, 0, stream>>>(x, sqb);
    knn_scan<32, 4><<<gscan, 256, 0, stream>>>(x, sqb, plist);
    mlp_kernel<32, 64, false, 3><<<pgrid, 384, 0, stream>>>(x, plist, T0, b1_0, W2_0, b2_0, nullptr, x0);

    // ---- layer 1: x0 (64) -> x1 (32), relu ----
    sq_kernel<64><<<sgrid, 256, 0, stream>>>(x0, sqb);
    knn_scan<64, 3><<<gscan, 256, 0, stream>>>(x0, sqb, plist);
    mlp_kernel<64, 32, false, 2><<<pgrid, 384, 0, stream>>>(x0, plist, T1, b1_1, W2_1, b2_1, nullptr, x1);

    // ---- layer 2: x1 (32) -> out (64), +x0 residual, relu ----
    sq_kernel<32><<<sgrid, 256, 0, stream>>>(x1, sqb);
    knn_scan<32, 4><<<gscan, 256, 0, stream>>>(x1, sqb, plist);
    mlp_kernel<32, 64, true, 3><<<pgrid, 384, 0, stream>>>(x1, plist, T2, b1_2, W2_2, b2_2, x0, outp);
}

// Round 7
// 855.130 us; speedup vs baseline: 1.4537x; 1.1662x over previous
//
#include <hip/hip_runtime.h>

#define NB   16
#define NN   2048
#define NPTS (NB * NN)
#define KNB  6

// ---------------- squared-norm kernel ----------------
template<int C>
__global__ void sq_kernel(const float* __restrict__ x, float* __restrict__ sq) {
    int i = blockIdx.x * blockDim.x + threadIdx.x;
    if (i >= NPTS) return;
    const float4* r = (const float4*)(x + (size_t)i * C);
    float s = 0.f;
#pragma unroll
    for (int c = 0; c < C / 4; ++c) {
        float4 f = r[c];
        s += f.x * f.x + f.y * f.y + f.z * f.z + f.w * f.w;
    }
    sq[i] = s;
}

// ---------------- weight prep: transpose the three W1s ----------------
__global__ void prep_w(const float* __restrict__ W10, const float* __restrict__ W11,
                       const float* __restrict__ W12,
                       float* __restrict__ T0, float* __restrict__ T1,
                       float* __restrict__ T2) {
    int t = blockIdx.x * 256 + threadIdx.x;
    if (t < 4096) { int o = t >> 6, c = t & 63;  T0[o * 64 + c]  = W10[c * 64 + o]; }
    if (t < 4096) { int o = t >> 7, c = t & 127; T1[o * 128 + c] = W11[c * 32 + o]; }
    if (t < 4096) { int o = t >> 6, c = t & 63;  T2[o * 64 + c]  = W12[c * 64 + o]; }
}

// branchless stable insert of (s, j) into ascending 6-list (round-4 validated)
__device__ __forceinline__ void insert6(float s, int j, float* dl, int* il) {
    float cd = s; int ci = j;
#pragma unroll
    for (int k = 0; k < 6; ++k) {
        const float od = dl[k]; const int oi = il[k];
        const bool c = cd < od;          // strict: existing wins ties -> stable
        dl[k] = c ? cd : od;
        il[k] = c ? ci : oi;
        cd = c ? od : cd;
        ci = c ? oi : ci;
    }
}

// ---------------- kNN scan kernel ----------------
// lane = query (Q rows of query features resident in VGPRs). Candidate rows +
// sq stream through the SCALAR pipe (wave-uniform s_load broadcast; FMA takes
// the SGPR operand directly — max-1-SGPR-per-VALU rule fits exactly).
// amdgpu_waves_per_eu(2,4) pins the allocator: VGPR floor 128, so the query
// arrays CANNOT be demoted (round-6 failure mode). Zero LDS. Branchless insert.
// grid (NN/(256*Q), NB, SPLN); block = 4 waves, same candidate range z.
template<int C, int Q, int SPLN>
__global__ __launch_bounds__(256) __attribute__((amdgpu_waves_per_eu(2, 4)))
void knn_scan(const float* __restrict__ x, const float* __restrict__ sq,
              unsigned long long* __restrict__ plist) {
    constexpr int RANGE = NN / SPLN;
    const int lane = threadIdx.x & 63;
    const int w    = threadIdx.x >> 6;
    const int b    = blockIdx.y;
    const int z    = blockIdx.z;
    const int base = b * NN;
    const int cbase = z * RANGE;
    const int q0 = blockIdx.x * (256 * Q) + w * (64 * Q) + lane;  // batch-local

    // Q query rows per lane, in registers
    float qr[Q][C];
    int   qidx[Q];
#pragma unroll
    for (int qq = 0; qq < Q; ++qq) {
        qidx[qq] = q0 + 64 * qq;
        const float* qp = x + (size_t)(base + qidx[qq]) * C;
#pragma unroll
        for (int c = 0; c < C; c += 4) {
            float4 f = *(const float4*)(qp + c);
            qr[qq][c] = f.x; qr[qq][c + 1] = f.y;
            qr[qq][c + 2] = f.z; qr[qq][c + 3] = f.w;
        }
    }

    float dl[Q][6]; int il[Q][6];
#pragma unroll
    for (int qq = 0; qq < Q; ++qq)
#pragma unroll
        for (int k = 0; k < 6; ++k) { dl[qq][k] = 1e30f; il[qq][k] = 0; }

    const float* rp  = x + (size_t)(base + cbase) * C;   // uniform base
    const float* sqp = sq + base + cbase;                // uniform base

    for (int j = 0; j < RANGE; ++j) {
        const float* row = rp + (size_t)j * C;           // uniform -> s_load
        float a[Q][4];
#pragma unroll
        for (int qq = 0; qq < Q; ++qq) {
            a[qq][0] = 0.f; a[qq][1] = 0.f; a[qq][2] = 0.f; a[qq][3] = 0.f;
        }
#pragma unroll
        for (int c = 0; c < C; ++c) {
            const float rv = row[c];                     // SGPR operand
#pragma unroll
            for (int qq = 0; qq < Q; ++qq)
                a[qq][c & 3] = fmaf(rv, qr[qq][c], a[qq][c & 3]);
        }
        const int jj = cbase + j;
        const float sj = sqp[j];
#pragma unroll
        for (int qq = 0; qq < Q; ++qq) {
            float s = fmaf(-2.f, (a[qq][0] + a[qq][1]) + (a[qq][2] + a[qq][3]), sj);
            s = (jj == qidx[qq]) ? 1e30f : s;            // self-exclusion
            insert6(s, jj, dl[qq], il[qq]);
        }
    }

    // packed sortable keys: (flip(score) << 11) | cand_idx (ascending)
#pragma unroll
    for (int qq = 0; qq < Q; ++qq) {
        unsigned long long* o = plist + ((size_t)z * NPTS + (base + qidx[qq])) * KNB;
#pragma unroll
        for (int k = 0; k < 6; ++k) {
            unsigned u = __float_as_uint(dl[qq][k]);
            u ^= (u & 0x80000000u) ? 0xFFFFFFFFu : 0x80000000u;
            o[k] = ((unsigned long long)u << 11) | (unsigned)(il[qq][k] & 2047);
        }
    }
}

// ---------------- kNN merge kernel ----------------
// thread = one query; merge SPLN sorted 6-lists -> top-6 global indices.
template<int SPLN>
__global__ __launch_bounds__(256) void knn_merge(const unsigned long long* __restrict__ plist,
                                                 int* __restrict__ nbr) {
    const int q = blockIdx.x * 256 + threadIdx.x;
    if (q >= NPTS) return;
    unsigned long long best[6];
#pragma unroll
    for (int k = 0; k < 6; ++k) best[k] = ~0ull;
    for (int cg = 0; cg < SPLN; ++cg) {
        const unsigned long long* p = plist + ((size_t)cg * NPTS + q) * KNB;
        for (int e = 0; e < 6; ++e) {
            unsigned long long v = p[e];
            if (v >= best[5]) break;   // sublist ascending
            best[5] = v;
#pragma unroll
            for (int k = 4; k >= 0; --k) {
                if (best[k + 1] < best[k]) {
                    unsigned long long t = best[k]; best[k] = best[k + 1]; best[k + 1] = t;
                }
            }
        }
    }
    const int b = q >> 11;
#pragma unroll
    for (int k = 0; k < 6; ++k)
        nbr[q * KNB + k] = (b << 11) | (int)(best[k] & 2047ull);
}

// ---------------- edge MLP kernel (round-4 version, verified fast) ----------------
// block = 384 thr = 6 waves; lane = point; wave = neighbor. Weight loads are
// wave-uniform scalar broadcasts; 6->1 max via 3-barrier LDS tree.
template<int CIN, int COUT, bool RESID, int MINW>
__global__ __launch_bounds__(384, MINW)
void mlp_kernel(const float* __restrict__ xin, const int* __restrict__ nbr,
                const float* __restrict__ W1T, const float* __restrict__ b1,
                const float* __restrict__ W2,  const float* __restrict__ b2,
                const float* __restrict__ resid, float* __restrict__ out) {
    constexpr int RS = COUT + 4;
    __shared__ float Buf[3][64][RS];

    const int lane = threadIdx.x & 63;
    const int w    = __builtin_amdgcn_readfirstlane(threadIdx.x >> 6);  // 0..5
    const int i    = blockIdx.x * 64 + lane;

    float xi[CIN], xd[CIN];
    {
        const float* xp = xin + (size_t)i * CIN;
#pragma unroll
        for (int c = 0; c < CIN; c += 4) {
            float4 f = *(const float4*)(xp + c);
            xi[c] = f.x; xi[c + 1] = f.y; xi[c + 2] = f.z; xi[c + 3] = f.w;
        }
        const int j = nbr[i * KNB + w];
        const float* jp = xin + (size_t)j * CIN;
#pragma unroll
        for (int c = 0; c < CIN; c += 4) {
            float4 f = *(const float4*)(jp + c);
            xd[c]     = f.x - xi[c];     xd[c + 1] = f.y - xi[c + 1];
            xd[c + 2] = f.z - xi[c + 2]; xd[c + 3] = f.w - xi[c + 3];
        }
    }

    float uacc[COUT];
#pragma unroll
    for (int o = 0; o < COUT; ++o) uacc[o] = 0.f;

    for (int op = 0; op < COUT; ++op) {
        const float* w1r = W1T + (size_t)op * (2 * CIN);
        float h0 = 0.f, h1 = 0.f, h2 = 0.f, h3 = 0.f;
#pragma unroll
        for (int c = 0; c < CIN; c += 4) {
            h0 = fmaf(w1r[c],     xi[c],     h0);
            h1 = fmaf(w1r[c + 1], xi[c + 1], h1);
            h2 = fmaf(w1r[c + 2], xi[c + 2], h2);
            h3 = fmaf(w1r[c + 3], xi[c + 3], h3);
        }
#pragma unroll
        for (int c = 0; c < CIN; c += 4) {
            h0 = fmaf(w1r[CIN + c],     xd[c],     h0);
            h1 = fmaf(w1r[CIN + c + 1], xd[c + 1], h1);
            h2 = fmaf(w1r[CIN + c + 2], xd[c + 2], h2);
            h3 = fmaf(w1r[CIN + c + 3], xd[c + 3], h3);
        }
        const float h = fmaxf((h0 + h1) + (h2 + h3) + b1[op], 0.f);
        const float* w2r = W2 + (size_t)op * COUT;
#pragma unroll
        for (int o = 0; o < COUT; ++o)
            uacc[o] = fmaf(w2r[o], h, uacc[o]);
    }

    if (w >= 3) {
#pragma unroll
        for (int o = 0; o < COUT; ++o) Buf[w - 3][lane][o] = uacc[o];
    }
    __syncthreads();
    if (w < 3) {
#pragma unroll
        for (int o = 0; o < COUT; ++o) uacc[o] = fmaxf(uacc[o], Buf[w][lane][o]);
    }
    __syncthreads();
    if (w == 1 || w == 2) {
#pragma unroll
        for (int o = 0; o < COUT; ++o) Buf[w][lane][o] = uacc[o];
    }
    __syncthreads();
    if (w == 0) {
        float* po = out + (size_t)i * COUT;
#pragma unroll
        for (int o = 0; o < COUT; ++o) {
            float v = fmaxf(uacc[o], fmaxf(Buf[1][lane][o], Buf[2][lane][o])) + b2[o];
            if (RESID) v += resid[(size_t)i * COUT + o];
            po[o] = fmaxf(v, 0.f);
        }
    }
}

extern "C" void kernel_launch(void* const* d_in, const int* in_sizes, int n_in,
                              void* d_out, int out_size, void* d_ws, size_t ws_size,
                              hipStream_t stream) {
    const float* x    = (const float*)d_in[0];
    const float* W1_0 = (const float*)d_in[2];
    const float* b1_0 = (const float*)d_in[3];
    const float* W2_0 = (const float*)d_in[4];
    const float* b2_0 = (const float*)d_in[5];
    const float* W1_1 = (const float*)d_in[6];
    const float* b1_1 = (const float*)d_in[7];
    const float* W2_1 = (const float*)d_in[8];
    const float* b2_1 = (const float*)d_in[9];
    const float* W1_2 = (const float*)d_in[10];
    const float* b1_2 = (const float*)d_in[11];
    const float* W2_2 = (const float*)d_in[12];
    const float* b2_2 = (const float*)d_in[13];
    float* outp = (float*)d_out;

    // workspace layout (plist first for 8B alignment); max SPLN = 16
    unsigned long long* plist = (unsigned long long*)d_ws;        // 16*NPTS*6
    float* x0  = (float*)(plist + (size_t)16 * NPTS * KNB);       // 32768 x 64
    float* x1  = x0 + (size_t)NPTS * 64;                          // 32768 x 32
    float* sqb = x1 + (size_t)NPTS * 32;                          // 32768
    float* T0  = sqb + NPTS;                                      // 64 x 64
    float* T1  = T0 + 4096;                                       // 32 x 128
    float* T2  = T1 + 4096;                                       // 64 x 64
    int*   nbr = (int*)(T2 + 4096);                               // 32768 x 6

    // C=32: Q=2, SPL=16 -> grid (4,16,16)  = 1024 blocks = 4096 waves (4/SIMD)
    // C=64: Q=1, SPL=8  -> grid (8,16,8)   = 1024 blocks = 4096 waves (4/SIMD)
    const dim3 g32(NN / 512, NB, 16);
    const dim3 g64(NN / 256, NB, 8);
    const int  sgrid = NPTS / 256;
    const int  pgrid = NPTS / 64;

    prep_w<<<16, 256, 0, stream>>>(W1_0, W1_1, W1_2, T0, T1, T2);

    // ---- layer 0: x (32) -> x0 (64), relu ----
    sq_kernel<32><<<sgrid, 256, 0, stream>>>(x, sqb);
    knn_scan<32, 2, 16><<<g32, 256, 0, stream>>>(x, sqb, plist);
    knn_merge<16><<<sgrid, 256, 0, stream>>>(plist, nbr);
    mlp_kernel<32, 64, false, 3><<<pgrid, 384, 0, stream>>>(x, nbr, T0, b1_0, W2_0, b2_0, nullptr, x0);

    // ---- layer 1: x0 (64) -> x1 (32), relu ----
    sq_kernel<64><<<sgrid, 256, 0, stream>>>(x0, sqb);
    knn_scan<64, 1, 8><<<g64, 256, 0, stream>>>(x0, sqb, plist);
    knn_merge<8><<<sgrid, 256, 0, stream>>>(plist, nbr);
    mlp_kernel<64, 32, false, 2><<<pgrid, 384, 0, stream>>>(x0, nbr, T1, b1_1, W2_1, b2_1, nullptr, x1);

    // ---- layer 2: x1 (32) -> out (64), +x0 residual, relu ----
    sq_kernel<32><<<sgrid, 256, 0, stream>>>(x1, sqb);
    knn_scan<32, 2, 16><<<g32, 256, 0, stream>>>(x1, sqb, plist);
    knn_merge<16><<<sgrid, 256, 0, stream>>>(plist, nbr);
    mlp_kernel<32, 64, true, 3><<<pgrid, 384, 0, stream>>>(x1, nbr, T2, b1_2, W2_2, b2_2, x0, outp);
}